// Round 19
// baseline (75.974 us; speedup 1.0000x reference)
//
#include <hip/hip_runtime.h>
#include <hip/hip_bf16.h>
#include <math.h>

#define HIDDEN 256
#define K_NBR 20
#define NB 1024

typedef __bf16 bf16x8 __attribute__((ext_vector_type(8)));
typedef float f32x4 __attribute__((ext_vector_type(4)));

__device__ __forceinline__ float wave_sum(float v) {
#pragma unroll
    for (int o = 32; o > 0; o >>= 1) v += __shfl_xor(v, o, 64);
    return v;
}

__device__ __forceinline__ void gload16(const void* g, void* l) {
    __builtin_amdgcn_global_load_lds(
        (const __attribute__((address_space(1))) void*)g,
        (__attribute__((address_space(3))) void*)l, 16, 0, 0);
}

// 3-bit swizzle: 16B-chunk g of row `row`, low 3 bits XOR'd with row&7
__device__ __forceinline__ int swz3(int g, int row) {
    return (g & ~7) | ((g & 7) ^ (row & 7));
}

// ---------------- attention + LayerNorm body (writes xb with swz3) ----------------
__device__ __forceinline__ void attn_ln_body(
    int b, int t, const int* __restrict__ node_idx, const int* __restrict__ topk,
    const float* __restrict__ node_emb, const float* __restrict__ fallback,
    const float* __restrict__ w_attn, const float* __restrict__ gamma,
    const float* __restrict__ beta, __bf16* __restrict__ xb,
    float* pe, float (*nbr)[HIDDEN], int* nidx, float* sc, float* red)
{
    int lane = t & 63, w = t >> 6;
    int nid = node_idx[b];
    bool valid = nid >= 0;
    int safe = valid ? nid : 0;

    pe[t] = valid ? node_emb[(size_t)safe * HIDDEN + t] + 1e-3f * fallback[t]
                  : fallback[t];
    if (t < K_NBR) nidx[t] = topk[safe * K_NBR + t];
    __syncthreads();
    for (int r = 0; r < K_NBR; ++r) {
        int gi = nidx[r];
        nbr[r][t] = (gi >= 0) ? node_emb[(size_t)gi * HIDDEN + t] : 0.f;
    }
    __syncthreads();
    float pe0 = pe[0];
    float wa[4];
#pragma unroll
    for (int q = 0; q < 4; ++q) wa[q] = w_attn[lane + 64 * q];
    for (int k = w; k < K_NBR; k += 4) {
        float p = 0.f;
#pragma unroll
        for (int q = 0; q < 4; ++q) p += nbr[k][lane + 64 * q] * wa[q];
        p = wave_sum(p);
        if (lane == 0) sc[k] = (nidx[k] >= 0) ? pe0 * p : -1e9f;
    }
    __syncthreads();
    bool has_valid = false;
#pragma unroll
    for (int k = 0; k < K_NBR; ++k) has_valid |= (nidx[k] >= 0);
    float mx = -1e30f;
#pragma unroll
    for (int k = 0; k < K_NBR; ++k) mx = fmaxf(mx, sc[k]);
    float at[K_NBR];
    float s = 0.f;
#pragma unroll
    for (int k = 0; k < K_NBR; ++k) { at[k] = expf(sc[k] - mx); s += at[k]; }
    float inv = has_valid ? 1.f / s : 0.f;
    float ctx = 0.f;
#pragma unroll
    for (int k = 0; k < K_NBR; ++k) ctx += (at[k] * inv) * nbr[k][t];
    float v0 = pe[t], v1 = ctx;
    float s1 = wave_sum(v0 + v1);
    float s2 = wave_sum(v0 * v0 + v1 * v1);
    if (lane == 0) { red[w] = s1; red[4 + w] = s2; }
    __syncthreads();
    s1 = red[0] + red[1] + red[2] + red[3];
    s2 = red[4] + red[5] + red[6] + red[7];
    float mu = s1 / 512.f;
    float var = s2 / 512.f - mu * mu;
    float rs = rsqrtf(var + 1e-5f);
    size_t base = (size_t)b * 512;
    int mask = b & 7;
    {
        int e = t;
        int g = e >> 3, off = e & 7;
        int gp = (g & ~7) | ((g & 7) ^ mask);
        xb[base + gp * 8 + off] = (__bf16)((v0 - mu) * rs * gamma[t] + beta[t]);
        e = 256 + t;
        g = e >> 3;
        gp = (g & ~7) | ((g & 7) ^ mask);
        xb[base + gp * 8 + off] = (__bf16)((v1 - mu) * rs * gamma[256 + t] + beta[256 + t]);
    }
}

// ---------------- transpose body: W fp32 [K,N] -> WT bf16 [Np,K] swz3 ---------------
__device__ __forceinline__ void transpose_body(
    const float* __restrict__ Wm, __bf16* __restrict__ WT,
    int Kd, int Nd, int Np, int bx, int by, int t)
{
    int n = bx * 64 + (t >> 2);
    int k0 = by * 32 + (t & 3) * 8;
    bool ok = n < Nd;
    bf16x8 v;
#pragma unroll
    for (int j = 0; j < 8; ++j) {
        float f = ok ? Wm[(size_t)(k0 + j) * Nd + n] : 0.f;
        v[j] = (__bf16)f;
    }
    if (n < Np) {
        int gp = swz3(k0 >> 3, n);
        *(bf16x8*)(WT + (size_t)n * Kd + gp * 8) = v;
    }
}

// ---------------- Fused prep: attn FIRST, then W1T, then W2T (R15-exact) -----
__global__ __launch_bounds__(256) void prep_kernel(
    const int* __restrict__ node_idx, const int* __restrict__ topk,
    const float* __restrict__ node_emb, const float* __restrict__ fallback,
    const float* __restrict__ w_attn, const float* __restrict__ gamma,
    const float* __restrict__ beta, const float* __restrict__ W1,
    const float* __restrict__ W2, __bf16* __restrict__ xb,
    __bf16* __restrict__ w1t, __bf16* __restrict__ w2t)
{
    __shared__ float pe[HIDDEN];
    __shared__ float nbr[K_NBR][HIDDEN];
    __shared__ int   nidx[K_NBR];
    __shared__ float sc[K_NBR];
    __shared__ float red[8];
    int bid = blockIdx.x;
    int t = threadIdx.x;
    if (bid < 1024) {
        attn_ln_body(bid, t, node_idx, topk, node_emb, fallback, w_attn, gamma,
                     beta, xb, pe, nbr, nidx, sc, red);
        return;
    }
    bid -= 1024;
    if (bid < 128) { transpose_body(W1, w1t, 512, 512, 512, bid % 8, bid / 8, t); return; }
    bid -= 128;
    transpose_body(W2, w2t, 512, 19920, 19968, bid % 312, bid / 312, t);
}

// ---------------- GEMM1: 64x64 tile, 4 waves, BK=64, counted vmcnt (R15-exact) ------------
__global__ __launch_bounds__(256, 4) void gemm1_kernel(
    const __bf16* __restrict__ A, const __bf16* __restrict__ BT,
    const float* __restrict__ bias, __bf16* __restrict__ Cb,
    int M, int N, int K)
{
    constexpr int BK = 64;
    __shared__ __bf16 As[2][64 * BK];
    __shared__ __bf16 Bs[2][64 * BK];

    int t = threadIdx.x;
    int lane = t & 63;
    int wid = t >> 6;
    int wm = wid >> 1, wn = wid & 1;
    int lo = lane & 15, hi = lane >> 4;

    int nwg = gridDim.x;                // 128
    int bid = blockIdx.x;
    int cpx = nwg >> 3;
    int lid = (bid & 7) * cpx + (bid >> 3);
    int m0 = (lid & 15) * 64;
    int n0 = (lid >> 4) * 64;

    int rsub = lane >> 3, kc = lane & 7;

    auto STAGE = [&](int buf, int k0) {
#pragma unroll
        for (int j = 0; j < 2; ++j) {
            int rb = j * 32 + wid * 8;
            gload16(A + (size_t)(m0 + rb + rsub) * K + k0 + kc * 8, &As[buf][rb * BK]);
        }
#pragma unroll
        for (int j = 0; j < 2; ++j) {
            int rb = j * 32 + wid * 8;
            gload16(BT + (size_t)(n0 + rb + rsub) * K + k0 + kc * 8, &Bs[buf][rb * BK]);
        }
    };

    f32x4 acc[2][2];
#pragma unroll
    for (int m = 0; m < 2; ++m)
#pragma unroll
        for (int n = 0; n < 2; ++n) acc[m][n] = (f32x4){0.f, 0.f, 0.f, 0.f};

    auto COMPUTE = [&](int buf) {
#pragma unroll
        for (int ks = 0; ks < 2; ++ks) {
            bf16x8 af[2], bfr[2];
#pragma unroll
            for (int m = 0; m < 2; ++m) {
                int r = wm * 32 + m * 16 + lo;
                af[m] = *(const bf16x8*)&As[buf][r * BK + (((ks * 4 + hi) ^ (r & 7)) * 8)];
            }
#pragma unroll
            for (int n = 0; n < 2; ++n) {
                int r = wn * 32 + n * 16 + lo;
                bfr[n] = *(const bf16x8*)&Bs[buf][r * BK + (((ks * 4 + hi) ^ (r & 7)) * 8)];
            }
#pragma unroll
            for (int m = 0; m < 2; ++m)
#pragma unroll
                for (int n = 0; n < 2; ++n)
                    acc[m][n] = __builtin_amdgcn_mfma_f32_16x16x32_bf16(
                        af[m], bfr[n], acc[m][n], 0, 0, 0);
        }
    };

    const int nt = K / BK;
    STAGE(0, 0);
    for (int tt = 0; tt < nt - 1; ++tt) {
        STAGE((tt + 1) & 1, (tt + 1) * BK);
        asm volatile("s_waitcnt vmcnt(4)" ::: "memory");
        __builtin_amdgcn_s_barrier();
        __builtin_amdgcn_sched_barrier(0);
        COMPUTE(tt & 1);
        __builtin_amdgcn_sched_barrier(0);
        __builtin_amdgcn_s_barrier();
    }
    asm volatile("s_waitcnt vmcnt(0)" ::: "memory");
    __builtin_amdgcn_s_barrier();
    __builtin_amdgcn_sched_barrier(0);
    COMPUTE((nt - 1) & 1);

#pragma unroll
    for (int m = 0; m < 2; ++m) {
        int gr = m0 + wm * 32 + m * 16 + hi * 4;
#pragma unroll
        for (int n = 0; n < 2; ++n) {
            int gc = n0 + wn * 32 + n * 16 + lo;
            float bv = bias[gc];
#pragma unroll
            for (int r = 0; r < 4; ++r) {
                float v = acc[m][n][r] + bv;
                float g = v * 0.5f * (1.f + erff(v * 0.70710678118f));
                int row = gr + r;
                int gp = swz3(gc >> 3, row);
                Cb[(size_t)row * N + gp * 8 + (gc & 7)] = (__bf16)g;
            }
        }
    }
}

// ---------------- GEMM2: 64x128 tile, BK=64, 8 waves of 32x32 — A DIRECT FROM GLOBAL -------
// R15 structure, but A-fragments load straight from swz3-stored global h (L2-hot, 1 MB):
// removes A from LDS entirely -> LDS 32 KB (B only) -> up to 4 blocks/CU, and halves
// LDS port traffic. vmcnt(2) counts only the 2 B-stage gload_lds ops (A-loads are
// consumed via compiler-inserted waits inside COMPUTE; stale outstanding counts only
// make the wait stricter, never looser).
__global__ __launch_bounds__(512, 6) void gemm2_kernel(
    const __bf16* __restrict__ A, const __bf16* __restrict__ BT,
    const float* __restrict__ bias, float* __restrict__ C,
    int M, int N, int K)
{
    constexpr int BK = 64;
    __shared__ __bf16 Bs[2][128 * BK];   // 16 KB each, 32 KB total

    int t = threadIdx.x;
    int lane = t & 63;
    int wid = t >> 6;                    // 0..7
    int wm = wid >> 2, wn = wid & 3;     // 2m x 4n wave grid, wave tile 32x32
    int lo = lane & 15, hi = lane >> 4;

    int nwg = gridDim.x;                 // 2496
    int bid = blockIdx.x;
    int cpx = nwg >> 3;                  // 312
    int lid = (bid & 7) * cpx + (bid >> 3);
    int m0 = (lid & 15) * 64;            // 16 m-panels
    int n0 = (lid >> 4) * 128;           // 156 n-panels

    int rsub = lane >> 3, kc = lane & 7;

    auto STAGE = [&](int buf, int k0) {
#pragma unroll
        for (int j = 0; j < 2; ++j) {
            int rb = j * 64 + wid * 8;
            gload16(BT + (size_t)(n0 + rb + rsub) * K + k0 + kc * 8, &Bs[buf][rb * BK]);
        }
    };

    f32x4 acc[2][2];
#pragma unroll
    for (int m = 0; m < 2; ++m)
#pragma unroll
        for (int n = 0; n < 2; ++n) acc[m][n] = (f32x4){0.f, 0.f, 0.f, 0.f};

    auto COMPUTE = [&](int buf, int tt) {
        int cb = tt * 8;                 // 16B-chunk base of this K-step
#pragma unroll
        for (int ks = 0; ks < 2; ++ks) {
            bf16x8 af[2], bfr[2];
#pragma unroll
            for (int m = 0; m < 2; ++m) {
                int r = wm * 32 + m * 16 + lo;
                // A direct from global (h stored swz3): offset = tt*64 + ((ks*4+hi)^(r&7))*8
                af[m] = *(const bf16x8*)(A + (size_t)(m0 + r) * K
                                           + (size_t)(cb + ((ks * 4 + hi) ^ (r & 7))) * 8);
            }
#pragma unroll
            for (int n = 0; n < 2; ++n) {
                int r = wn * 32 + n * 16 + lo;
                bfr[n] = *(const bf16x8*)&Bs[buf][r * BK + (((ks * 4 + hi) ^ (r & 7)) * 8)];
            }
#pragma unroll
            for (int m = 0; m < 2; ++m)
#pragma unroll
                for (int n = 0; n < 2; ++n)
                    acc[m][n] = __builtin_amdgcn_mfma_f32_16x16x32_bf16(
                        af[m], bfr[n], acc[m][n], 0, 0, 0);
        }
    };

    const int nt = K / BK;               // 8
    STAGE(0, 0);
    for (int tt = 0; tt < nt - 1; ++tt) {
        STAGE((tt + 1) & 1, (tt + 1) * BK);
        asm volatile("s_waitcnt vmcnt(2)" ::: "memory");   // B(tt) landed; B(tt+1) in flight
        __builtin_amdgcn_s_barrier();
        __builtin_amdgcn_sched_barrier(0);
        COMPUTE(tt & 1, tt);
        __builtin_amdgcn_sched_barrier(0);
        __builtin_amdgcn_s_barrier();                      // Bs[tt] free for restage
    }
    asm volatile("s_waitcnt vmcnt(0)" ::: "memory");
    __builtin_amdgcn_s_barrier();
    __builtin_amdgcn_sched_barrier(0);
    COMPUTE((nt - 1) & 1, nt - 1);

#pragma unroll
    for (int m = 0; m < 2; ++m) {
        int gr = m0 + wm * 32 + m * 16 + hi * 4;
#pragma unroll
        for (int n = 0; n < 2; ++n) {
            int gc = n0 + wn * 32 + n * 16 + lo;
            if (gc < N) {
                float bv = bias[gc];
#pragma unroll
                for (int r = 0; r < 4; ++r)
                    C[(size_t)(gr + r) * N + gc] = acc[m][n][r] + bv;
            }
        }
    }
}

extern "C" void kernel_launch(void* const* d_in, const int* in_sizes, int n_in,
                              void* d_out, int out_size, void* d_ws, size_t ws_size,
                              hipStream_t stream) {
    const int*   node_idx = (const int*)d_in[0];
    const int*   topk     = (const int*)d_in[1];
    const float* node_emb = (const float*)d_in[2];
    const float* fallback = (const float*)d_in[3];
    const float* w_attn   = (const float*)d_in[4];
    const float* gamma    = (const float*)d_in[5];
    const float* beta     = (const float*)d_in[6];
    const float* W1       = (const float*)d_in[7];
    const float* b1       = (const float*)d_in[8];
    const float* W2       = (const float*)d_in[9];
    const float* b2       = (const float*)d_in[10];
    float* out = (float*)d_out;

    const int M = 1024, Kd = 512, N1 = 512, N2 = 19920;

    __bf16* xb  = (__bf16*)d_ws;                      // [1024, 512]
    __bf16* h   = xb + (size_t)M * Kd;                // [1024, 512]
    __bf16* w1t = h + (size_t)M * Kd;                 // [512, 512]
    __bf16* w2t = w1t + (size_t)N1 * Kd;              // [19968, 512]

    // attn (0..1023) | W1T (1024..1151) | W2T (1152..6143)
    prep_kernel<<<1024 + 128 + 4992, 256, 0, stream>>>(
        node_idx, topk, node_emb, fallback, w_attn, gamma, beta, W1, W2,
        xb, w1t, w2t);

    gemm1_kernel<<<dim3(128), 256, 0, stream>>>(
        xb, w1t, b1, h, M, N1, Kd);

    // 16m x 156n = 2496 blocks, 64x128 tile, A-direct gemm2
    gemm2_kernel<<<dim3(2496), 512, 0, stream>>>(
        h, w2t, b2, out, M, N2, Kd);
    (void)ws_size;
}

// Round 20
// 69.304 us; speedup vs baseline: 1.0963x; 1.0963x over previous
//
#include <hip/hip_runtime.h>
#include <hip/hip_bf16.h>
#include <math.h>

#define HIDDEN 256
#define K_NBR 20
#define NB 1024

typedef __bf16 bf16x8 __attribute__((ext_vector_type(8)));
typedef float f32x4 __attribute__((ext_vector_type(4)));

__device__ __forceinline__ float wave_sum(float v) {
#pragma unroll
    for (int o = 32; o > 0; o >>= 1) v += __shfl_xor(v, o, 64);
    return v;
}

__device__ __forceinline__ void gload16(const void* g, void* l) {
    __builtin_amdgcn_global_load_lds(
        (const __attribute__((address_space(1))) void*)g,
        (__attribute__((address_space(3))) void*)l, 16, 0, 0);
}

// 3-bit swizzle: 16B-chunk g of row `row`, low 3 bits XOR'd with row&7
__device__ __forceinline__ int swz3(int g, int row) {
    return (g & ~7) | ((g & 7) ^ (row & 7));
}

// ---------------- attention + LayerNorm body (writes xb with swz3) ----------------
__device__ __forceinline__ void attn_ln_body(
    int b, int t, const int* __restrict__ node_idx, const int* __restrict__ topk,
    const float* __restrict__ node_emb, const float* __restrict__ fallback,
    const float* __restrict__ w_attn, const float* __restrict__ gamma,
    const float* __restrict__ beta, __bf16* __restrict__ xb,
    float* pe, float (*nbr)[HIDDEN], int* nidx, float* sc, float* red)
{
    int lane = t & 63, w = t >> 6;
    int nid = node_idx[b];
    bool valid = nid >= 0;
    int safe = valid ? nid : 0;

    pe[t] = valid ? node_emb[(size_t)safe * HIDDEN + t] + 1e-3f * fallback[t]
                  : fallback[t];
    if (t < K_NBR) nidx[t] = topk[safe * K_NBR + t];
    __syncthreads();
    for (int r = 0; r < K_NBR; ++r) {
        int gi = nidx[r];
        nbr[r][t] = (gi >= 0) ? node_emb[(size_t)gi * HIDDEN + t] : 0.f;
    }
    __syncthreads();
    float pe0 = pe[0];
    float wa[4];
#pragma unroll
    for (int q = 0; q < 4; ++q) wa[q] = w_attn[lane + 64 * q];
    for (int k = w; k < K_NBR; k += 4) {
        float p = 0.f;
#pragma unroll
        for (int q = 0; q < 4; ++q) p += nbr[k][lane + 64 * q] * wa[q];
        p = wave_sum(p);
        if (lane == 0) sc[k] = (nidx[k] >= 0) ? pe0 * p : -1e9f;
    }
    __syncthreads();
    bool has_valid = false;
#pragma unroll
    for (int k = 0; k < K_NBR; ++k) has_valid |= (nidx[k] >= 0);
    float mx = -1e30f;
#pragma unroll
    for (int k = 0; k < K_NBR; ++k) mx = fmaxf(mx, sc[k]);
    float at[K_NBR];
    float s = 0.f;
#pragma unroll
    for (int k = 0; k < K_NBR; ++k) { at[k] = expf(sc[k] - mx); s += at[k]; }
    float inv = has_valid ? 1.f / s : 0.f;
    float ctx = 0.f;
#pragma unroll
    for (int k = 0; k < K_NBR; ++k) ctx += (at[k] * inv) * nbr[k][t];
    float v0 = pe[t], v1 = ctx;
    float s1 = wave_sum(v0 + v1);
    float s2 = wave_sum(v0 * v0 + v1 * v1);
    if (lane == 0) { red[w] = s1; red[4 + w] = s2; }
    __syncthreads();
    s1 = red[0] + red[1] + red[2] + red[3];
    s2 = red[4] + red[5] + red[6] + red[7];
    float mu = s1 / 512.f;
    float var = s2 / 512.f - mu * mu;
    float rs = rsqrtf(var + 1e-5f);
    size_t base = (size_t)b * 512;
    int mask = b & 7;
    {
        int e = t;
        int g = e >> 3, off = e & 7;
        int gp = (g & ~7) | ((g & 7) ^ mask);
        xb[base + gp * 8 + off] = (__bf16)((v0 - mu) * rs * gamma[t] + beta[t]);
        e = 256 + t;
        g = e >> 3;
        gp = (g & ~7) | ((g & 7) ^ mask);
        xb[base + gp * 8 + off] = (__bf16)((v1 - mu) * rs * gamma[256 + t] + beta[256 + t]);
    }
}

// ---------------- transpose body: W fp32 [K,N] -> WT bf16 [Np,K] swz3 ---------------
__device__ __forceinline__ void transpose_body(
    const float* __restrict__ Wm, __bf16* __restrict__ WT,
    int Kd, int Nd, int Np, int bx, int by, int t)
{
    int n = bx * 64 + (t >> 2);
    int k0 = by * 32 + (t & 3) * 8;
    bool ok = n < Nd;
    bf16x8 v;
#pragma unroll
    for (int j = 0; j < 8; ++j) {
        float f = ok ? Wm[(size_t)(k0 + j) * Nd + n] : 0.f;
        v[j] = (__bf16)f;
    }
    if (n < Np) {
        int gp = swz3(k0 >> 3, n);
        *(bf16x8*)(WT + (size_t)n * Kd + gp * 8) = v;
    }
}

// ---------------- Fused prep: attn FIRST, then W1T, then W2T (uniform tail) -----
__global__ __launch_bounds__(256) void prep_kernel(
    const int* __restrict__ node_idx, const int* __restrict__ topk,
    const float* __restrict__ node_emb, const float* __restrict__ fallback,
    const float* __restrict__ w_attn, const float* __restrict__ gamma,
    const float* __restrict__ beta, const float* __restrict__ W1,
    const float* __restrict__ W2, __bf16* __restrict__ xb,
    __bf16* __restrict__ w1t, __bf16* __restrict__ w2t)
{
    __shared__ float pe[HIDDEN];
    __shared__ float nbr[K_NBR][HIDDEN];
    __shared__ int   nidx[K_NBR];
    __shared__ float sc[K_NBR];
    __shared__ float red[8];
    int bid = blockIdx.x;
    int t = threadIdx.x;
    if (bid < 1024) {
        attn_ln_body(bid, t, node_idx, topk, node_emb, fallback, w_attn, gamma,
                     beta, xb, pe, nbr, nidx, sc, red);
        return;
    }
    bid -= 1024;
    if (bid < 128) { transpose_body(W1, w1t, 512, 512, 512, bid % 8, bid / 8, t); return; }
    bid -= 128;
    transpose_body(W2, w2t, 512, 19920, 19968, bid % 312, bid / 312, t);
}

// ---------------- GEMM1: 64x64 tile, 4 waves, BK=64, counted vmcnt (R11-proven) ------------
__global__ __launch_bounds__(256, 4) void gemm1_kernel(
    const __bf16* __restrict__ A, const __bf16* __restrict__ BT,
    const float* __restrict__ bias, __bf16* __restrict__ Cb,
    int M, int N, int K)
{
    constexpr int BK = 64;
    __shared__ __bf16 As[2][64 * BK];
    __shared__ __bf16 Bs[2][64 * BK];

    int t = threadIdx.x;
    int lane = t & 63;
    int wid = t >> 6;
    int wm = wid >> 1, wn = wid & 1;
    int lo = lane & 15, hi = lane >> 4;

    int nwg = gridDim.x;                // 128
    int bid = blockIdx.x;
    int cpx = nwg >> 3;
    int lid = (bid & 7) * cpx + (bid >> 3);
    int m0 = (lid & 15) * 64;
    int n0 = (lid >> 4) * 64;

    int rsub = lane >> 3, kc = lane & 7;

    auto STAGE = [&](int buf, int k0) {
#pragma unroll
        for (int j = 0; j < 2; ++j) {
            int rb = j * 32 + wid * 8;
            gload16(A + (size_t)(m0 + rb + rsub) * K + k0 + kc * 8, &As[buf][rb * BK]);
        }
#pragma unroll
        for (int j = 0; j < 2; ++j) {
            int rb = j * 32 + wid * 8;
            gload16(BT + (size_t)(n0 + rb + rsub) * K + k0 + kc * 8, &Bs[buf][rb * BK]);
        }
    };

    f32x4 acc[2][2];
#pragma unroll
    for (int m = 0; m < 2; ++m)
#pragma unroll
        for (int n = 0; n < 2; ++n) acc[m][n] = (f32x4){0.f, 0.f, 0.f, 0.f};

    auto COMPUTE = [&](int buf) {
#pragma unroll
        for (int ks = 0; ks < 2; ++ks) {
            bf16x8 af[2], bfr[2];
#pragma unroll
            for (int m = 0; m < 2; ++m) {
                int r = wm * 32 + m * 16 + lo;
                af[m] = *(const bf16x8*)&As[buf][r * BK + (((ks * 4 + hi) ^ (r & 7)) * 8)];
            }
#pragma unroll
            for (int n = 0; n < 2; ++n) {
                int r = wn * 32 + n * 16 + lo;
                bfr[n] = *(const bf16x8*)&Bs[buf][r * BK + (((ks * 4 + hi) ^ (r & 7)) * 8)];
            }
#pragma unroll
            for (int m = 0; m < 2; ++m)
#pragma unroll
                for (int n = 0; n < 2; ++n)
                    acc[m][n] = __builtin_amdgcn_mfma_f32_16x16x32_bf16(
                        af[m], bfr[n], acc[m][n], 0, 0, 0);
        }
    };

    const int nt = K / BK;
    STAGE(0, 0);
    for (int tt = 0; tt < nt - 1; ++tt) {
        STAGE((tt + 1) & 1, (tt + 1) * BK);
        asm volatile("s_waitcnt vmcnt(4)" ::: "memory");
        __builtin_amdgcn_s_barrier();
        __builtin_amdgcn_sched_barrier(0);
        COMPUTE(tt & 1);
        __builtin_amdgcn_sched_barrier(0);
        __builtin_amdgcn_s_barrier();
    }
    asm volatile("s_waitcnt vmcnt(0)" ::: "memory");
    __builtin_amdgcn_s_barrier();
    __builtin_amdgcn_sched_barrier(0);
    COMPUTE((nt - 1) & 1);

#pragma unroll
    for (int m = 0; m < 2; ++m) {
        int gr = m0 + wm * 32 + m * 16 + hi * 4;
#pragma unroll
        for (int n = 0; n < 2; ++n) {
            int gc = n0 + wn * 32 + n * 16 + lo;
            float bv = bias[gc];
#pragma unroll
            for (int r = 0; r < 4; ++r) {
                float v = acc[m][n][r] + bv;
                float g = v * 0.5f * (1.f + erff(v * 0.70710678118f));
                int row = gr + r;
                int gp = swz3(gc >> 3, row);
                Cb[(size_t)row * N + gp * 8 + (gc & 7)] = (__bf16)g;
            }
        }
    }
}

// ---------------- GEMM2 (R15-exact): 64x128 tile, BK=64, 8 waves of 32x32, 48 KB LDS -------
__global__ __launch_bounds__(512, 6) void gemm2_kernel(
    const __bf16* __restrict__ A, const __bf16* __restrict__ BT,
    const float* __restrict__ bias, float* __restrict__ C,
    int M, int N, int K)
{
    constexpr int BK = 64;
    __shared__ __bf16 As[2][64 * BK];    // 8 KB each
    __shared__ __bf16 Bs[2][128 * BK];   // 16 KB each

    int t = threadIdx.x;
    int lane = t & 63;
    int wid = t >> 6;                    // 0..7
    int wm = wid >> 2, wn = wid & 3;     // 2m x 4n wave grid, wave tile 32x32
    int lo = lane & 15, hi = lane >> 4;

    int nwg = gridDim.x;                 // 2496
    int bid = blockIdx.x;
    int cpx = nwg >> 3;                  // 312
    int lid = (bid & 7) * cpx + (bid >> 3);
    int m0 = (lid & 15) * 64;            // 16 m-panels
    int n0 = (lid >> 4) * 128;           // 156 n-panels

    int rsub = lane >> 3, kc = lane & 7;

    auto STAGE = [&](int buf, int k0) {
        gload16(A + (size_t)(m0 + wid * 8 + rsub) * K + k0 + kc * 8,
                &As[buf][(wid * 8) * BK]);
#pragma unroll
        for (int j = 0; j < 2; ++j) {
            int rb = j * 64 + wid * 8;
            gload16(BT + (size_t)(n0 + rb + rsub) * K + k0 + kc * 8, &Bs[buf][rb * BK]);
        }
    };

    f32x4 acc[2][2];
#pragma unroll
    for (int m = 0; m < 2; ++m)
#pragma unroll
        for (int n = 0; n < 2; ++n) acc[m][n] = (f32x4){0.f, 0.f, 0.f, 0.f};

    auto COMPUTE = [&](int buf) {
#pragma unroll
        for (int ks = 0; ks < 2; ++ks) {
            bf16x8 af[2], bfr[2];
#pragma unroll
            for (int m = 0; m < 2; ++m) {
                int r = wm * 32 + m * 16 + lo;
                af[m] = *(const bf16x8*)&As[buf][r * BK + (((ks * 4 + hi) ^ (r & 7)) * 8)];
            }
#pragma unroll
            for (int n = 0; n < 2; ++n) {
                int r = wn * 32 + n * 16 + lo;
                bfr[n] = *(const bf16x8*)&Bs[buf][r * BK + (((ks * 4 + hi) ^ (r & 7)) * 8)];
            }
#pragma unroll
            for (int m = 0; m < 2; ++m)
#pragma unroll
                for (int n = 0; n < 2; ++n)
                    acc[m][n] = __builtin_amdgcn_mfma_f32_16x16x32_bf16(
                        af[m], bfr[n], acc[m][n], 0, 0, 0);
        }
    };

    const int nt = K / BK;               // 8
    STAGE(0, 0);
    for (int tt = 0; tt < nt - 1; ++tt) {
        STAGE((tt + 1) & 1, (tt + 1) * BK);
        asm volatile("s_waitcnt vmcnt(3)" ::: "memory");
        __builtin_amdgcn_s_barrier();
        __builtin_amdgcn_sched_barrier(0);
        COMPUTE(tt & 1);
        __builtin_amdgcn_sched_barrier(0);
        __builtin_amdgcn_s_barrier();
    }
    asm volatile("s_waitcnt vmcnt(0)" ::: "memory");
    __builtin_amdgcn_s_barrier();
    __builtin_amdgcn_sched_barrier(0);
    COMPUTE((nt - 1) & 1);

#pragma unroll
    for (int m = 0; m < 2; ++m) {
        int gr = m0 + wm * 32 + m * 16 + hi * 4;
#pragma unroll
        for (int n = 0; n < 2; ++n) {
            int gc = n0 + wn * 32 + n * 16 + lo;
            if (gc < N) {
                float bv = bias[gc];
#pragma unroll
                for (int r = 0; r < 4; ++r)
                    C[(size_t)(gr + r) * N + gc] = acc[m][n][r] + bv;
            }
        }
    }
}

extern "C" void kernel_launch(void* const* d_in, const int* in_sizes, int n_in,
                              void* d_out, int out_size, void* d_ws, size_t ws_size,
                              hipStream_t stream) {
    const int*   node_idx = (const int*)d_in[0];
    const int*   topk     = (const int*)d_in[1];
    const float* node_emb = (const float*)d_in[2];
    const float* fallback = (const float*)d_in[3];
    const float* w_attn   = (const float*)d_in[4];
    const float* gamma    = (const float*)d_in[5];
    const float* beta     = (const float*)d_in[6];
    const float* W1       = (const float*)d_in[7];
    const float* b1       = (const float*)d_in[8];
    const float* W2       = (const float*)d_in[9];
    const float* b2       = (const float*)d_in[10];
    float* out = (float*)d_out;

    const int M = 1024, Kd = 512, N1 = 512, N2 = 19920;

    __bf16* xb  = (__bf16*)d_ws;                      // [1024, 512]
    __bf16* h   = xb + (size_t)M * Kd;                // [1024, 512]
    __bf16* w1t = h + (size_t)M * Kd;                 // [512, 512]
    __bf16* w2t = w1t + (size_t)N1 * Kd;              // [19968, 512]

    // attn (0..1023) | W1T (1024..1151) | W2T (1152..6143)
    prep_kernel<<<1024 + 128 + 4992, 256, 0, stream>>>(
        node_idx, topk, node_emb, fallback, w_attn, gamma, beta, W1, W2,
        xb, w1t, w2t);

    gemm1_kernel<<<dim3(128), 256, 0, stream>>>(
        xb, w1t, b1, h, M, N1, Kd);

    // 16m x 156n = 2496 blocks, 64x128 tile, 3 blocks/CU
    gemm2_kernel<<<dim3(2496), 512, 0, stream>>>(
        h, w2t, b2, out, M, N2, Kd);
    (void)ws_size;
}